// Round 27
// baseline (416.771 us; speedup 1.0000x reference)
//
#include <hip/hip_runtime.h>

#define NN 50000
#define NE 640000
#define BNEPS 1e-5f
#define NBANK 16   // banks for stats(x)
#define NBANKG 64  // banks for gather-fused stats
#define CAP 64     // padded ELL row capacity (λ=12.8, max deg ≈ 30)
#define NBUCK 256
#define BUCKW 196  // ceil(NN/NBUCK)
#define BCAP 3008  // bucket capacity (expected 2509, σ≈50)

// workspace layout (float offsets) — total 15,325,952 floats = 61.3 MB
#define OFF_CURSOR 51200     // NN ints
#define OFF_ESRC 102400      // NN*CAP ushorts = 1.6M floats -> ends 1702400
#define OFF_WT0 1702400
#define OFF_WT1 1710592
#define OFF_WT2 1718784
#define OFF_STATS 1726976    // 28672 floats -> ends 1755648
#define OFF_BCUR 1755648     // 256 ints -> ends 1755904
#define OFF_EBUF 1755904     // NBUCK*BCAP uints = 770048 -> ends 2525952
#define OFF_B0 2525952
#define OFF_B1 8925952

typedef __attribute__((ext_vector_type(8))) __bf16 bf16x8;
typedef __attribute__((ext_vector_type(4))) float f32x4;

// ---- bf16 helpers ----
__device__ __forceinline__ float uplo(unsigned int u) {
  unsigned int v = u << 16;
  return __builtin_bit_cast(float, v);
}
__device__ __forceinline__ float uphi(unsigned int u) {
  unsigned int v = u & 0xffff0000u;
  return __builtin_bit_cast(float, v);
}
__device__ __forceinline__ unsigned int f2bf(float f) {
  unsigned int u = __builtin_bit_cast(unsigned int, f);
  return (u + 0x7fffu + ((u >> 16) & 1u)) >> 16;  // RNE
}

// ====== K0: wtrans + cursor init + zero stats + zero bucket cursors ========
__global__ __launch_bounds__(256) void prep_k(
    const float* __restrict__ W0, const float* __restrict__ W1,
    const float* __restrict__ W2, unsigned short* __restrict__ T0,
    unsigned short* __restrict__ T1, unsigned short* __restrict__ T2,
    int* __restrict__ cursor, float* __restrict__ stats,
    int* __restrict__ bcur) {
  const int bid = blockIdx.x;
  const int tid = threadIdx.x;
  if (bid < 160) {
    int f = bid * 256 + tid;
    if (f < 16384) {
      int k = f >> 7, n = f & 127;
      T0[n * 128 + k] = (unsigned short)f2bf(W0[f]);
    } else if (f < 32768) {
      int g = f - 16384;
      int k = g >> 7, n = g & 127;
      T1[n * 128 + k] = (unsigned short)f2bf(W1[g]);
    } else if (f < 40960) {
      int g = f - 32768;
      int k = g >> 6, n = g & 63;
      T2[n * 128 + k] = (unsigned short)f2bf(W2[g]);
    }
  } else if (bid < 356) {
    int i = (bid - 160) * 256 + tid;
    if (i < NN) cursor[i] = i * CAP;
  } else if (bid < 468) {
    int j = (bid - 356) * 256 + tid;  // 112 blocks x 256 = 28672 exactly
    stats[j] = 0.0f;
  } else {
    if (tid < NBUCK) bcur[tid] = 0;
  }
}

// ---- BN-stats body (f32 input, plain); 16-banked atomic finalize ----
template <int NC>
__device__ __forceinline__ void bn_stats_body(
    int sbid, int nsb, int tid, const float* __restrict__ A,
    float* __restrict__ sums, float* __restrict__ sqs, float (*rs)[NC],
    float (*rq)[NC]) {
  constexpr int CG = NC / 4;
  constexpr int RG = 256 / CG;
  const int tc = tid % CG;
  const int tr = tid / CG;
  float s0 = 0, s1 = 0, s2 = 0, s3 = 0, q0 = 0, q1 = 0, q2 = 0, q3 = 0;
  const int stride = nsb * RG;
  for (int r = sbid * RG + tr; r < NN; r += stride) {
    float4 v = *(const float4*)&A[(size_t)r * NC + tc * 4];
    s0 += v.x; s1 += v.y; s2 += v.z; s3 += v.w;
    q0 += v.x * v.x; q1 += v.y * v.y; q2 += v.z * v.z; q3 += v.w * v.w;
  }
  rs[tr][tc * 4] = s0; rs[tr][tc * 4 + 1] = s1;
  rs[tr][tc * 4 + 2] = s2; rs[tr][tc * 4 + 3] = s3;
  rq[tr][tc * 4] = q0; rq[tr][tc * 4 + 1] = q1;
  rq[tr][tc * 4 + 2] = q2; rq[tr][tc * 4 + 3] = q3;
  __syncthreads();
  if (tr == 0) {
    const int bank = (sbid & (NBANK - 1)) * NC;
    for (int j = 0; j < 4; ++j) {
      int c = tc * 4 + j;
      float ts = 0, tq = 0;
      for (int g = 0; g < RG; ++g) { ts += rs[g][c]; tq += rq[g][c]; }
      atomicAdd(&sums[bank + c], ts);
      atomicAdd(&sqs[bank + c], tq);
    }
  }
}

// ===== K1: bn_stats(x) [1024] ∥ bucket pass A (all edges, clamped) =========
__global__ __launch_bounds__(256) void stats_bucketA_k(
    const float* __restrict__ x, float* __restrict__ s0,
    float* __restrict__ q0, const int* __restrict__ src,
    const int* __restrict__ dst, int* __restrict__ bcur,
    unsigned int* __restrict__ ebuf) {
  __shared__ float rs[8][128];
  __shared__ float rq[8][128];
  const int bid = blockIdx.x;
  if (bid < 1024) {
    bn_stats_body<128>(bid, 1024, threadIdx.x, x, s0, q0, rs, rq);
  } else {
    int e = (bid - 1024) * 256 + threadIdx.x;
    if (e < NE) {
      const int d = dst[e];
      const int b = d / BUCKW;          // 0..255 (d < 50000)
      const int p = atomicAdd(&bcur[b], 1);
      if (p < BCAP)                     // defensive: never triggers (10σ)
        ebuf[b * BCAP + p] = ((unsigned int)d << 16) | (unsigned int)src[e];
    }
  }
}

// ===== K2: fused GEMM1→LDS→conv1 [782] ∥ bucket pass B (ELL, clamped) ======
__global__ __launch_bounds__(256) void fused12_bucketB_k(
    const float* __restrict__ x, const unsigned short* __restrict__ Wt0,
    const unsigned short* __restrict__ Wt1, const float* __restrict__ proj_b,
    const float* __restrict__ s0, const float* __restrict__ q0,
    const float* __restrict__ g0, const float* __restrict__ b0,
    unsigned short* __restrict__ Ybf, const int* __restrict__ bcur,
    const unsigned int* __restrict__ ebuf, int* __restrict__ cursor,
    unsigned short* __restrict__ esrc) {
  __shared__ __align__(16) char smem[17408];
  __shared__ float af_s[128];
  __shared__ float bf_s[128];
  __shared__ float pb_s[128];
  const int bid = blockIdx.x;
  const int tid = threadIdx.x;
  if (bid >= 782) {
    const int b = bid - 782;  // bucket id 0..255
    int nb = bcur[b];
    if (nb > BCAP) nb = BCAP;  // defensive clamp
    const unsigned int* eb = &ebuf[b * BCAP];
    for (int i = tid; i < nb; i += 256) {
      const unsigned int u = eb[i];
      const int d = (int)(u >> 16);
      const int s = (int)(u & 0xffffu);
      const int p = atomicAdd(&cursor[d], 1);
      if (p < (d + 1) * CAP)  // defensive: row capacity (never triggers)
        esrc[p] = (unsigned short)s;
    }
    return;
  }
  const int row0 = bid * 64;
  if (tid < 128) {
    float s = 0.f, q = 0.f;
#pragma unroll
    for (int b = 0; b < NBANK; ++b) {
      s += s0[b * 128 + tid];
      q += q0[b * 128 + tid];
    }
    float m = s * (1.0f / NN);
    float v = q * (1.0f / NN) - m * m;
    float a = g0[tid] * rsqrtf(v + BNEPS);
    af_s[tid] = a;
    bf_s[tid] = b0[tid] - m * a;
    pb_s[tid] = proj_b[tid];
  }
  __syncthreads();
  for (int f = tid; f < 64 * 32; f += 256) {
    const int r = f >> 5;
    const int c4 = f & 31;
    const int rg = row0 + r;
    float4 v = make_float4(0.f, 0.f, 0.f, 0.f);
    if (rg < NN) {
      v = *(const float4*)&x[(size_t)rg * 128 + c4 * 4];
      const float4 a4 = *(const float4*)&af_s[c4 * 4];
      const float4 b4 = *(const float4*)&bf_s[c4 * 4];
      v.x = fmaf(a4.x, v.x, b4.x);
      v.y = fmaf(a4.y, v.y, b4.y);
      v.z = fmaf(a4.z, v.z, b4.z);
      v.w = fmaf(a4.w, v.w, b4.w);
    }
    uint2 wv;
    wv.x = f2bf(v.x) | (f2bf(v.y) << 16);
    wv.y = f2bf(v.z) | (f2bf(v.w) << 16);
    const int ba = (r * 256 + c4 * 8) ^ ((r & 7) << 4);
    *(uint2*)(smem + ba) = wv;
  }
  __syncthreads();

  const int w = tid >> 6;
  const int l = tid & 63;
  const int lr = l & 15;
  const int lg = l >> 4;
  const int arow = w * 16 + lr;
  f32x4 acc[8];
#pragma unroll
  for (int i = 0; i < 8; ++i) acc[i] = (f32x4){0.f, 0.f, 0.f, 0.f};
#pragma unroll
  for (int kt = 0; kt < 4; ++kt) {
    const int ba = (arow * 256 + kt * 64 + lg * 16) ^ ((arow & 7) << 4);
    bf16x8 a = __builtin_bit_cast(bf16x8, *(const uint4*)(smem + ba));
#pragma unroll
    for (int nt = 0; nt < 8; ++nt) {
      bf16x8 b = __builtin_bit_cast(
          bf16x8,
          *(const uint4*)&Wt0[(size_t)(nt * 16 + lr) * 128 + kt * 32 + lg * 8]);
      acc[nt] = __builtin_amdgcn_mfma_f32_16x16x32_bf16(a, b, acc[nt], 0, 0, 0);
    }
  }
  __syncthreads();
#pragma unroll
  for (int nt = 0; nt < 8; ++nt) {
    const float pb = pb_s[nt * 16 + lr];
#pragma unroll
    for (int r = 0; r < 4; ++r) {
      const int row = w * 16 + lg * 4 + r;
      const float hv = fmaxf(acc[nt][r] + pb, 0.f);
      const int ba = (row * 256 + (nt * 16 + lr) * 2) ^ ((row & 7) << 4);
      *(unsigned short*)(smem + ba) = (unsigned short)f2bf(hv);
    }
  }
  __syncthreads();
  f32x4 acc2[8];
#pragma unroll
  for (int i = 0; i < 8; ++i) acc2[i] = (f32x4){0.f, 0.f, 0.f, 0.f};
#pragma unroll
  for (int kt = 0; kt < 4; ++kt) {
    const int ba = (arow * 256 + kt * 64 + lg * 16) ^ ((arow & 7) << 4);
    bf16x8 a = __builtin_bit_cast(bf16x8, *(const uint4*)(smem + ba));
#pragma unroll
    for (int nt = 0; nt < 8; ++nt) {
      bf16x8 b = __builtin_bit_cast(
          bf16x8,
          *(const uint4*)&Wt1[(size_t)(nt * 16 + lr) * 128 + kt * 32 + lg * 8]);
      acc2[nt] =
          __builtin_amdgcn_mfma_f32_16x16x32_bf16(a, b, acc2[nt], 0, 0, 0);
    }
  }
  float* Cl = (float*)smem;
  const int tcx = tid % 32;
  const int trx = tid / 32;
#pragma unroll
  for (int half = 0; half < 2; ++half) {
    __syncthreads();
    if ((w >> 1) == half) {
#pragma unroll
      for (int nt = 0; nt < 8; ++nt)
#pragma unroll
        for (int r = 0; r < 4; ++r)
          Cl[((w & 1) * 16 + lg * 4 + r) * 132 + nt * 16 + lr] = acc2[nt][r];
    }
    __syncthreads();
#pragma unroll
    for (int i = 0; i < 4; ++i) {
      const int rl = trx * 4 + i;
      const int rg = row0 + half * 32 + rl;
      if (rg < NN) {
        float4 v = *(const float4*)&Cl[rl * 132 + tcx * 4];
        uint2 o;
        o.x = f2bf(v.x) | (f2bf(v.y) << 16);
        o.y = f2bf(v.z) | (f2bf(v.w) << 16);
        *(uint2*)&Ybf[(size_t)rg * 128 + tcx * 4] = o;
      }
    }
  }
}

// ======= gather + fused BN stats (shfl row-reduce; clamped row window) =====
template <int NC, int OUTBF>
__global__ __launch_bounds__(256) void gather_bf_k(
    const int* __restrict__ cursor, const unsigned short* __restrict__ esrc,
    const unsigned short* __restrict__ Y, void* __restrict__ outp,
    const float* __restrict__ cb, float* __restrict__ sums,
    float* __restrict__ sqs) {
  constexpr int CG = NC / 8;
  constexpr int RG = 256 / CG;
  __shared__ float ws_s[4][NC];
  __shared__ float ws_q[4][NC];
  const int tid = threadIdx.x;
  const int tc = tid % CG;
  const int tr = tid / CG;
  const int n = blockIdx.x * RG + tr;
  const bool act = (n < NN);
  const int c = tc * 8;
  float z[8];
#pragma unroll
  for (int j = 0; j < 8; ++j) z[j] = 0.f;
  if (act) {
    const int beg = n * CAP;
    int end = cursor[n];
    if (end > beg + CAP) end = beg + CAP;  // defensive clamp
    const float dn = rsqrtf((float)(end - beg) + 1.0f);
    float a[8];
    {
      const uint4 p = *(const uint4*)&Y[(size_t)n * NC + c];
      a[0] = dn * uplo(p.x); a[1] = dn * uphi(p.x);
      a[2] = dn * uplo(p.y); a[3] = dn * uphi(p.y);
      a[4] = dn * uplo(p.z); a[5] = dn * uphi(p.z);
      a[6] = dn * uplo(p.w); a[7] = dn * uphi(p.w);
    }
    int e = beg;
    for (; e + 2 <= end; e += 2) {
      const int s0 = esrc[e];
      const int s1 = esrc[e + 1];
      const float d0 = rsqrtf((float)(cursor[s0] - s0 * CAP) + 1.0f);
      const float d1 = rsqrtf((float)(cursor[s1] - s1 * CAP) + 1.0f);
      const uint4 q0 = *(const uint4*)&Y[(size_t)s0 * NC + c];
      const uint4 q1 = *(const uint4*)&Y[(size_t)s1 * NC + c];
      a[0] = fmaf(d0, uplo(q0.x), a[0]); a[1] = fmaf(d0, uphi(q0.x), a[1]);
      a[2] = fmaf(d0, uplo(q0.y), a[2]); a[3] = fmaf(d0, uphi(q0.y), a[3]);
      a[4] = fmaf(d0, uplo(q0.z), a[4]); a[5] = fmaf(d0, uphi(q0.z), a[5]);
      a[6] = fmaf(d0, uplo(q0.w), a[6]); a[7] = fmaf(d0, uphi(q0.w), a[7]);
      a[0] = fmaf(d1, uplo(q1.x), a[0]); a[1] = fmaf(d1, uphi(q1.x), a[1]);
      a[2] = fmaf(d1, uplo(q1.y), a[2]); a[3] = fmaf(d1, uphi(q1.y), a[3]);
      a[4] = fmaf(d1, uplo(q1.z), a[4]); a[5] = fmaf(d1, uphi(q1.z), a[5]);
      a[6] = fmaf(d1, uplo(q1.w), a[6]); a[7] = fmaf(d1, uphi(q1.w), a[7]);
    }
    if (e < end) {
      const int s0 = esrc[e];
      const float d0 = rsqrtf((float)(cursor[s0] - s0 * CAP) + 1.0f);
      const uint4 q0 = *(const uint4*)&Y[(size_t)s0 * NC + c];
      a[0] = fmaf(d0, uplo(q0.x), a[0]); a[1] = fmaf(d0, uphi(q0.x), a[1]);
      a[2] = fmaf(d0, uplo(q0.y), a[2]); a[3] = fmaf(d0, uphi(q0.y), a[3]);
      a[4] = fmaf(d0, uplo(q0.z), a[4]); a[5] = fmaf(d0, uphi(q0.z), a[5]);
      a[6] = fmaf(d0, uplo(q0.w), a[6]); a[7] = fmaf(d0, uphi(q0.w), a[7]);
    }
#pragma unroll
    for (int j = 0; j < 8; ++j) z[j] = fmaf(dn, a[j], cb[c + j]);
    if constexpr (OUTBF == 1) {
      unsigned int p[4];
#pragma unroll
      for (int j = 0; j < 4; ++j)
        p[j] = f2bf(z[2 * j]) | (f2bf(z[2 * j + 1]) << 16);
      *(uint4*)&((unsigned short*)outp)[(size_t)n * NC + c] =
          make_uint4(p[0], p[1], p[2], p[3]);
    } else {
      float* Z = (float*)outp;
      *(float4*)&Z[(size_t)n * NC + c] = make_float4(z[0], z[1], z[2], z[3]);
      *(float4*)&Z[(size_t)n * NC + c + 4] =
          make_float4(z[4], z[5], z[6], z[7]);
    }
  }
  float s[8], q[8];
#pragma unroll
  for (int j = 0; j < 8; ++j) { s[j] = z[j]; q[j] = z[j] * z[j]; }
#pragma unroll
  for (int off = CG; off < 64; off <<= 1) {
#pragma unroll
    for (int j = 0; j < 8; ++j) {
      s[j] += __shfl_xor(s[j], off);
      q[j] += __shfl_xor(q[j], off);
    }
  }
  const int w = tid >> 6;
  const int l = tid & 63;
  if (l < CG) {
    *(float4*)&ws_s[w][c] = make_float4(s[0], s[1], s[2], s[3]);
    *(float4*)&ws_s[w][c + 4] = make_float4(s[4], s[5], s[6], s[7]);
    *(float4*)&ws_q[w][c] = make_float4(q[0], q[1], q[2], q[3]);
    *(float4*)&ws_q[w][c + 4] = make_float4(q[4], q[5], q[6], q[7]);
  }
  __syncthreads();
  if (tid < NC) {
    float ts = 0.f, tq = 0.f;
#pragma unroll
    for (int g = 0; g < 4; ++g) { ts += ws_s[g][tid]; tq += ws_q[g][tid]; }
    const int bank = (blockIdx.x % NBANKG) * NC;
    atomicAdd(&sums[bank + tid], ts);
    atomicAdd(&sqs[bank + tid], tq);
  }
}

// ---------------- conv2 GEMM (bf16 in, affine+relu staging, bf16 out) ------
__global__ __launch_bounds__(256) void conv2_k(
    const unsigned short* __restrict__ Z1, const unsigned short* __restrict__ Wt,
    const float* __restrict__ sums, const float* __restrict__ sqs,
    const float* __restrict__ gamma, const float* __restrict__ beta,
    unsigned short* __restrict__ O1) {
  __shared__ __align__(16) char smem[16384];
  __shared__ float af_s[128];
  __shared__ float bf_s[128];
  const int tid = threadIdx.x;
  const int row0 = blockIdx.x * 64;
  if (tid < 128) {
    float s = 0.f, q = 0.f;
#pragma unroll
    for (int b = 0; b < NBANKG; ++b) {
      s += sums[b * 128 + tid];
      q += sqs[b * 128 + tid];
    }
    float m = s * (1.0f / NN);
    float v = q * (1.0f / NN) - m * m;
    float a = gamma[tid] * rsqrtf(v + BNEPS);
    af_s[tid] = a;
    bf_s[tid] = beta[tid] - m * a;
  }
  __syncthreads();
  for (int f = tid; f < 64 * 16; f += 256) {
    const int r = f >> 4;
    const int c8 = f & 15;
    const int rg = row0 + r;
    uint4 w4 = make_uint4(0u, 0u, 0u, 0u);
    if (rg < NN) {
      const uint4 raw = *(const uint4*)&Z1[(size_t)rg * 128 + c8 * 8];
      const int cc = c8 * 8;
      float e[8] = {uplo(raw.x), uphi(raw.x), uplo(raw.y), uphi(raw.y),
                    uplo(raw.z), uphi(raw.z), uplo(raw.w), uphi(raw.w)};
      unsigned int p[4];
#pragma unroll
      for (int j = 0; j < 4; ++j) {
        float lo = fmaxf(fmaf(af_s[cc + 2 * j], e[2 * j], bf_s[cc + 2 * j]), 0.f);
        float hi = fmaxf(
            fmaf(af_s[cc + 2 * j + 1], e[2 * j + 1], bf_s[cc + 2 * j + 1]), 0.f);
        p[j] = f2bf(lo) | (f2bf(hi) << 16);
      }
      w4 = make_uint4(p[0], p[1], p[2], p[3]);
    }
    const int ba = (r * 256 + c8 * 16) ^ ((r & 7) << 4);
    *(uint4*)(smem + ba) = w4;
  }
  __syncthreads();
  const int w = tid >> 6;
  const int l = tid & 63;
  const int lr = l & 15;
  const int lg = l >> 4;
  const int arow = w * 16 + lr;
  f32x4 acc[4];
#pragma unroll
  for (int i = 0; i < 4; ++i) acc[i] = (f32x4){0.f, 0.f, 0.f, 0.f};
#pragma unroll
  for (int kt = 0; kt < 4; ++kt) {
    const int ba = (arow * 256 + kt * 64 + lg * 16) ^ ((arow & 7) << 4);
    bf16x8 a = __builtin_bit_cast(bf16x8, *(const uint4*)(smem + ba));
#pragma unroll
    for (int nt = 0; nt < 4; ++nt) {
      bf16x8 b = __builtin_bit_cast(
          bf16x8,
          *(const uint4*)&Wt[(size_t)(nt * 16 + lr) * 128 + kt * 32 + lg * 8]);
      acc[nt] = __builtin_amdgcn_mfma_f32_16x16x32_bf16(a, b, acc[nt], 0, 0, 0);
    }
  }
  float* Cl = (float*)smem;
  const int tcx = tid % 16;
  const int trx = tid / 16;
#pragma unroll
  for (int half = 0; half < 2; ++half) {
    __syncthreads();
    if ((w >> 1) == half) {
#pragma unroll
      for (int nt = 0; nt < 4; ++nt)
#pragma unroll
        for (int r = 0; r < 4; ++r)
          Cl[((w & 1) * 16 + lg * 4 + r) * 68 + nt * 16 + lr] = acc[nt][r];
    }
    __syncthreads();
#pragma unroll
    for (int i = 0; i < 2; ++i) {
      const int rl = trx * 2 + i;
      const int rg = row0 + half * 32 + rl;
      if (rg < NN) {
        float4 v = *(const float4*)&Cl[rl * 68 + tcx * 4];
        uint2 o;
        o.x = f2bf(v.x) | (f2bf(v.y) << 16);
        o.y = f2bf(v.z) | (f2bf(v.w) << 16);
        *(uint2*)&O1[(size_t)rg * 64 + tcx * 4] = o;
      }
    }
  }
}

// ---------------- final: out = af*z2 + bf ----------------
__global__ __launch_bounds__(256) void final_k(
    const float* __restrict__ Z2, const float* __restrict__ s2,
    const float* __restrict__ q2, const float* __restrict__ gamma,
    const float* __restrict__ beta, float* __restrict__ out) {
  __shared__ float af_s[64];
  __shared__ float bf_s[64];
  if (threadIdx.x < 64) {
    float s = 0.f, q = 0.f;
#pragma unroll
    for (int b = 0; b < NBANKG; ++b) {
      s += s2[b * 64 + threadIdx.x];
      q += q2[b * 64 + threadIdx.x];
    }
    float m = s * (1.0f / NN);
    float v = q * (1.0f / NN) - m * m;
    float a = gamma[threadIdx.x] * rsqrtf(v + BNEPS);
    af_s[threadIdx.x] = a;
    bf_s[threadIdx.x] = beta[threadIdx.x] - m * a;
  }
  __syncthreads();
  const int u = blockIdx.x * 256 + threadIdx.x;
  if (u >= NN * 16) return;
  const int r = u >> 4;
  const int c = (u & 15) * 4;
  float4 v = *(const float4*)&Z2[(size_t)r * 64 + c];
  const float4 a4 = *(const float4*)&af_s[c];
  const float4 b4 = *(const float4*)&bf_s[c];
  float4 o;
  o.x = fmaf(a4.x, v.x, b4.x);
  o.y = fmaf(a4.y, v.y, b4.y);
  o.z = fmaf(a4.z, v.z, b4.z);
  o.w = fmaf(a4.w, v.w, b4.w);
  *(float4*)&out[(size_t)r * 64 + c] = o;
}

extern "C" void kernel_launch(void* const* d_in, const int* in_sizes, int n_in,
                              void* d_out, int out_size, void* d_ws,
                              size_t ws_size, hipStream_t stream) {
  const float* x = (const float*)d_in[0];
  const int* ei = (const int*)d_in[1];
  const int* src = ei;
  const int* dst = ei + NE;
  const float* bn_in_g = (const float*)d_in[2];
  const float* bn_in_b = (const float*)d_in[3];
  const float* bn1_g = (const float*)d_in[4];
  const float* bn1_b = (const float*)d_in[5];
  const float* bn2_g = (const float*)d_in[6];
  const float* bn2_b = (const float*)d_in[7];
  const float* proj_W = (const float*)d_in[8];
  const float* proj_b = (const float*)d_in[9];
  const float* conv1_W = (const float*)d_in[10];
  const float* conv1_b = (const float*)d_in[11];
  const float* conv2_W = (const float*)d_in[12];
  const float* conv2_b = (const float*)d_in[13];
  float* out = (float*)d_out;

  float* ws = (float*)d_ws;
  int* cursor = (int*)(ws + OFF_CURSOR);
  unsigned short* esrc = (unsigned short*)(ws + OFF_ESRC);  // padded ELL
  unsigned short* Wt0 = (unsigned short*)(ws + OFF_WT0);
  unsigned short* Wt1 = (unsigned short*)(ws + OFF_WT1);
  unsigned short* Wt2 = (unsigned short*)(ws + OFF_WT2);
  float* st = ws + OFF_STATS;
  float* s0 = st;              // 16 x 128
  float* q0 = st + 2048;       // 16 x 128
  float* s1 = st + 4096;       // 64 x 128
  float* q1 = st + 12288;      // 64 x 128
  float* s2 = st + 20480;      // 64 x 64
  float* q2 = st + 24576;      // 64 x 64
  int* bcur = (int*)(ws + OFF_BCUR);
  unsigned int* ebuf = (unsigned int*)(ws + OFF_EBUF);
  float* B0 = ws + OFF_B0;
  float* B1 = ws + OFF_B1;
  // sequential aliasing
  unsigned short* Ybf = (unsigned short*)B1;   // K2 out, gather1 in
  unsigned short* Z1bf = (unsigned short*)B0;  // gather1 out
  unsigned short* Y2bf = (unsigned short*)B1;  // conv2 out (Ybf dead)
  float* Z2 = B0;                              // gather2 out (Z1 dead)

  // K0: wtrans + cursor init + zero stats + zero bucket cursors
  prep_k<<<469, 256, 0, stream>>>(proj_W, conv1_W, conv2_W, Wt0, Wt1, Wt2,
                                  cursor, st, bcur);
  // K1: bn_stats(x) [1024, 16-bank] ∥ bucket pass A [2500]
  stats_bucketA_k<<<3524, 256, 0, stream>>>(x, s0, q0, src, dst, bcur, ebuf);
  // K2: fused GEMM1→LDS→conv1 → Ybf [782] ∥ bucket pass B → ELL [256]
  fused12_bucketB_k<<<1038, 256, 0, stream>>>(x, Wt0, Wt1, proj_b, s0, q0,
                                              bn_in_g, bn_in_b, Ybf, bcur,
                                              ebuf, cursor, esrc);
  // K3: gather1 → z1 bf16 + fused BN1 stats [3125, 64-bank]
  gather_bf_k<128, 1><<<3125, 256, 0, stream>>>(cursor, esrc, Ybf, Z1bf,
                                                conv1_b, s1, q1);
  // K4: conv2 GEMM (relu(BN1(z1)) staging, plain bf16 out)
  conv2_k<<<782, 256, 0, stream>>>(Z1bf, Wt2, s1, q1, bn1_g, bn1_b, Y2bf);
  // K5: gather2 → z2 f32 + fused BN2 stats [1563, 64-bank]
  gather_bf_k<64, 0><<<1563, 256, 0, stream>>>(cursor, esrc, Y2bf, Z2, conv2_b,
                                               s2, q2);
  // K6: final BN apply (pure affine on z2)
  final_k<<<(NN * 16 + 255) / 256, 256, 0, stream>>>(Z2, s2, q2, bn2_g, bn2_b,
                                                     out);
}

// Round 28
// 215.123 us; speedup vs baseline: 1.9374x; 1.9374x over previous
//
#include <hip/hip_runtime.h>

#define NN 50000
#define NE 640000
#define BNEPS 1e-5f
#define NBANK 16   // banks for stats(x)
#define NBANKG 64  // banks for gather-fused stats
#define CAP 64     // padded ELL row capacity (λ=12.8, max deg ≈ 30)
#define NBUCK 2048
#define BUCKW 25   // ceil(NN/NBUCK)
#define BCAP 512   // bucket capacity (expected 320, σ≈18, >10σ headroom)

// workspace layout (float offsets) — total 15,606,272 floats = 62.4 MB
#define OFF_CURSOR 51200     // NN ints
#define OFF_ESRC 102400      // NN*CAP ushorts = 1.6M floats -> ends 1702400
#define OFF_WT0 1702400
#define OFF_WT1 1710592
#define OFF_WT2 1718784
#define OFF_STATS 1726976    // 28672 floats -> ends 1755648
#define OFF_BCUR 1755648     // 2048 ints -> ends 1757696
#define OFF_EBUF 1757696     // NBUCK*BCAP uints = 1048576 -> ends 2806272
#define OFF_B0 2806272
#define OFF_B1 9206272

typedef __attribute__((ext_vector_type(8))) __bf16 bf16x8;
typedef __attribute__((ext_vector_type(4))) float f32x4;

// ---- bf16 helpers ----
__device__ __forceinline__ float uplo(unsigned int u) {
  unsigned int v = u << 16;
  return __builtin_bit_cast(float, v);
}
__device__ __forceinline__ float uphi(unsigned int u) {
  unsigned int v = u & 0xffff0000u;
  return __builtin_bit_cast(float, v);
}
__device__ __forceinline__ unsigned int f2bf(float f) {
  unsigned int u = __builtin_bit_cast(unsigned int, f);
  return (u + 0x7fffu + ((u >> 16) & 1u)) >> 16;  // RNE
}

// ====== K0: wtrans + cursor init + zero stats + zero bucket cursors ========
__global__ __launch_bounds__(256) void prep_k(
    const float* __restrict__ W0, const float* __restrict__ W1,
    const float* __restrict__ W2, unsigned short* __restrict__ T0,
    unsigned short* __restrict__ T1, unsigned short* __restrict__ T2,
    int* __restrict__ cursor, float* __restrict__ stats,
    int* __restrict__ bcur) {
  const int bid = blockIdx.x;
  const int tid = threadIdx.x;
  if (bid < 160) {
    int f = bid * 256 + tid;
    if (f < 16384) {
      int k = f >> 7, n = f & 127;
      T0[n * 128 + k] = (unsigned short)f2bf(W0[f]);
    } else if (f < 32768) {
      int g = f - 16384;
      int k = g >> 7, n = g & 127;
      T1[n * 128 + k] = (unsigned short)f2bf(W1[g]);
    } else if (f < 40960) {
      int g = f - 32768;
      int k = g >> 6, n = g & 63;
      T2[n * 128 + k] = (unsigned short)f2bf(W2[g]);
    }
  } else if (bid < 356) {
    int i = (bid - 160) * 256 + tid;
    if (i < NN) cursor[i] = i * CAP;
  } else if (bid < 468) {
    int j = (bid - 356) * 256 + tid;  // 112 blocks x 256 = 28672 exactly
    stats[j] = 0.0f;
  } else {
    int j = (bid - 468) * 256 + tid;  // 8 blocks x 256 = 2048 exactly
    if (j < NBUCK) bcur[j] = 0;
  }
}

// ---- BN-stats body (f32 input, plain); 16-banked atomic finalize ----
template <int NC>
__device__ __forceinline__ void bn_stats_body(
    int sbid, int nsb, int tid, const float* __restrict__ A,
    float* __restrict__ sums, float* __restrict__ sqs, float (*rs)[NC],
    float (*rq)[NC]) {
  constexpr int CG = NC / 4;
  constexpr int RG = 256 / CG;
  const int tc = tid % CG;
  const int tr = tid / CG;
  float s0 = 0, s1 = 0, s2 = 0, s3 = 0, q0 = 0, q1 = 0, q2 = 0, q3 = 0;
  const int stride = nsb * RG;
  for (int r = sbid * RG + tr; r < NN; r += stride) {
    float4 v = *(const float4*)&A[(size_t)r * NC + tc * 4];
    s0 += v.x; s1 += v.y; s2 += v.z; s3 += v.w;
    q0 += v.x * v.x; q1 += v.y * v.y; q2 += v.z * v.z; q3 += v.w * v.w;
  }
  rs[tr][tc * 4] = s0; rs[tr][tc * 4 + 1] = s1;
  rs[tr][tc * 4 + 2] = s2; rs[tr][tc * 4 + 3] = s3;
  rq[tr][tc * 4] = q0; rq[tr][tc * 4 + 1] = q1;
  rq[tr][tc * 4 + 2] = q2; rq[tr][tc * 4 + 3] = q3;
  __syncthreads();
  if (tr == 0) {
    const int bank = (sbid & (NBANK - 1)) * NC;
    for (int j = 0; j < 4; ++j) {
      int c = tc * 4 + j;
      float ts = 0, tq = 0;
      for (int g = 0; g < RG; ++g) { ts += rs[g][c]; tq += rq[g][c]; }
      atomicAdd(&sums[bank + c], ts);
      atomicAdd(&sqs[bank + c], tq);
    }
  }
}

// ===== K1: bn_stats(x) [1024] ∥ bucket pass A (all edges, clamped) =========
__global__ __launch_bounds__(256) void stats_bucketA_k(
    const float* __restrict__ x, float* __restrict__ s0,
    float* __restrict__ q0, const int* __restrict__ src,
    const int* __restrict__ dst, int* __restrict__ bcur,
    unsigned int* __restrict__ ebuf) {
  __shared__ float rs[8][128];
  __shared__ float rq[8][128];
  const int bid = blockIdx.x;
  if (bid < 1024) {
    bn_stats_body<128>(bid, 1024, threadIdx.x, x, s0, q0, rs, rq);
  } else {
    int e = (bid - 1024) * 256 + threadIdx.x;
    if (e < NE) {
      const int d = dst[e];
      const int b = d / BUCKW;          // 0..2047 (d < 50000)
      const int p = atomicAdd(&bcur[b], 1);
      if (p < BCAP)                     // defensive: never triggers (>10σ)
        ebuf[b * BCAP + p] = ((unsigned int)d << 16) | (unsigned int)src[e];
    }
  }
}

// ===== K2: fused GEMM1→LDS→conv1 [782] ∥ bucket pass B (ELL, clamped) ======
__global__ __launch_bounds__(256) void fused12_bucketB_k(
    const float* __restrict__ x, const unsigned short* __restrict__ Wt0,
    const unsigned short* __restrict__ Wt1, const float* __restrict__ proj_b,
    const float* __restrict__ s0, const float* __restrict__ q0,
    const float* __restrict__ g0, const float* __restrict__ b0,
    unsigned short* __restrict__ Ybf, const int* __restrict__ bcur,
    const unsigned int* __restrict__ ebuf, int* __restrict__ cursor,
    unsigned short* __restrict__ esrc) {
  __shared__ __align__(16) char smem[17408];
  __shared__ float af_s[128];
  __shared__ float bf_s[128];
  __shared__ float pb_s[128];
  const int bid = blockIdx.x;
  const int tid = threadIdx.x;
  if (bid >= 782) {
    const int b = bid - 782;  // bucket id 0..2047
    int nb = bcur[b];
    if (nb > BCAP) nb = BCAP;  // defensive clamp
    const unsigned int* eb = &ebuf[b * BCAP];
    for (int i = tid; i < nb; i += 256) {
      const unsigned int u = eb[i];
      const int d = (int)(u >> 16);
      const int s = (int)(u & 0xffffu);
      const int p = atomicAdd(&cursor[d], 1);
      if (p < (d + 1) * CAP)  // defensive: row capacity (never triggers)
        esrc[p] = (unsigned short)s;
    }
    return;
  }
  const int row0 = bid * 64;
  if (tid < 128) {
    float s = 0.f, q = 0.f;
#pragma unroll
    for (int b = 0; b < NBANK; ++b) {
      s += s0[b * 128 + tid];
      q += q0[b * 128 + tid];
    }
    float m = s * (1.0f / NN);
    float v = q * (1.0f / NN) - m * m;
    float a = g0[tid] * rsqrtf(v + BNEPS);
    af_s[tid] = a;
    bf_s[tid] = b0[tid] - m * a;
    pb_s[tid] = proj_b[tid];
  }
  __syncthreads();
  for (int f = tid; f < 64 * 32; f += 256) {
    const int r = f >> 5;
    const int c4 = f & 31;
    const int rg = row0 + r;
    float4 v = make_float4(0.f, 0.f, 0.f, 0.f);
    if (rg < NN) {
      v = *(const float4*)&x[(size_t)rg * 128 + c4 * 4];
      const float4 a4 = *(const float4*)&af_s[c4 * 4];
      const float4 b4 = *(const float4*)&bf_s[c4 * 4];
      v.x = fmaf(a4.x, v.x, b4.x);
      v.y = fmaf(a4.y, v.y, b4.y);
      v.z = fmaf(a4.z, v.z, b4.z);
      v.w = fmaf(a4.w, v.w, b4.w);
    }
    uint2 wv;
    wv.x = f2bf(v.x) | (f2bf(v.y) << 16);
    wv.y = f2bf(v.z) | (f2bf(v.w) << 16);
    const int ba = (r * 256 + c4 * 8) ^ ((r & 7) << 4);
    *(uint2*)(smem + ba) = wv;
  }
  __syncthreads();

  const int w = tid >> 6;
  const int l = tid & 63;
  const int lr = l & 15;
  const int lg = l >> 4;
  const int arow = w * 16 + lr;
  f32x4 acc[8];
#pragma unroll
  for (int i = 0; i < 8; ++i) acc[i] = (f32x4){0.f, 0.f, 0.f, 0.f};
#pragma unroll
  for (int kt = 0; kt < 4; ++kt) {
    const int ba = (arow * 256 + kt * 64 + lg * 16) ^ ((arow & 7) << 4);
    bf16x8 a = __builtin_bit_cast(bf16x8, *(const uint4*)(smem + ba));
#pragma unroll
    for (int nt = 0; nt < 8; ++nt) {
      bf16x8 b = __builtin_bit_cast(
          bf16x8,
          *(const uint4*)&Wt0[(size_t)(nt * 16 + lr) * 128 + kt * 32 + lg * 8]);
      acc[nt] = __builtin_amdgcn_mfma_f32_16x16x32_bf16(a, b, acc[nt], 0, 0, 0);
    }
  }
  __syncthreads();
#pragma unroll
  for (int nt = 0; nt < 8; ++nt) {
    const float pb = pb_s[nt * 16 + lr];
#pragma unroll
    for (int r = 0; r < 4; ++r) {
      const int row = w * 16 + lg * 4 + r;
      const float hv = fmaxf(acc[nt][r] + pb, 0.f);
      const int ba = (row * 256 + (nt * 16 + lr) * 2) ^ ((row & 7) << 4);
      *(unsigned short*)(smem + ba) = (unsigned short)f2bf(hv);
    }
  }
  __syncthreads();
  f32x4 acc2[8];
#pragma unroll
  for (int i = 0; i < 8; ++i) acc2[i] = (f32x4){0.f, 0.f, 0.f, 0.f};
#pragma unroll
  for (int kt = 0; kt < 4; ++kt) {
    const int ba = (arow * 256 + kt * 64 + lg * 16) ^ ((arow & 7) << 4);
    bf16x8 a = __builtin_bit_cast(bf16x8, *(const uint4*)(smem + ba));
#pragma unroll
    for (int nt = 0; nt < 8; ++nt) {
      bf16x8 b = __builtin_bit_cast(
          bf16x8,
          *(const uint4*)&Wt1[(size_t)(nt * 16 + lr) * 128 + kt * 32 + lg * 8]);
      acc2[nt] =
          __builtin_amdgcn_mfma_f32_16x16x32_bf16(a, b, acc2[nt], 0, 0, 0);
    }
  }
  float* Cl = (float*)smem;
  const int tcx = tid % 32;
  const int trx = tid / 32;
#pragma unroll
  for (int half = 0; half < 2; ++half) {
    __syncthreads();
    if ((w >> 1) == half) {
#pragma unroll
      for (int nt = 0; nt < 8; ++nt)
#pragma unroll
        for (int r = 0; r < 4; ++r)
          Cl[((w & 1) * 16 + lg * 4 + r) * 132 + nt * 16 + lr] = acc2[nt][r];
    }
    __syncthreads();
#pragma unroll
    for (int i = 0; i < 4; ++i) {
      const int rl = trx * 4 + i;
      const int rg = row0 + half * 32 + rl;
      if (rg < NN) {
        float4 v = *(const float4*)&Cl[rl * 132 + tcx * 4];
        uint2 o;
        o.x = f2bf(v.x) | (f2bf(v.y) << 16);
        o.y = f2bf(v.z) | (f2bf(v.w) << 16);
        *(uint2*)&Ybf[(size_t)rg * 128 + tcx * 4] = o;
      }
    }
  }
}

// ======= gather + fused BN stats (shfl row-reduce; clamped row window) =====
template <int NC, int OUTBF>
__global__ __launch_bounds__(256) void gather_bf_k(
    const int* __restrict__ cursor, const unsigned short* __restrict__ esrc,
    const unsigned short* __restrict__ Y, void* __restrict__ outp,
    const float* __restrict__ cb, float* __restrict__ sums,
    float* __restrict__ sqs) {
  constexpr int CG = NC / 8;
  constexpr int RG = 256 / CG;
  __shared__ float ws_s[4][NC];
  __shared__ float ws_q[4][NC];
  const int tid = threadIdx.x;
  const int tc = tid % CG;
  const int tr = tid / CG;
  const int n = blockIdx.x * RG + tr;
  const bool act = (n < NN);
  const int c = tc * 8;
  float z[8];
#pragma unroll
  for (int j = 0; j < 8; ++j) z[j] = 0.f;
  if (act) {
    const int beg = n * CAP;
    int end = cursor[n];
    if (end > beg + CAP) end = beg + CAP;  // defensive clamp
    const float dn = rsqrtf((float)(end - beg) + 1.0f);
    float a[8];
    {
      const uint4 p = *(const uint4*)&Y[(size_t)n * NC + c];
      a[0] = dn * uplo(p.x); a[1] = dn * uphi(p.x);
      a[2] = dn * uplo(p.y); a[3] = dn * uphi(p.y);
      a[4] = dn * uplo(p.z); a[5] = dn * uphi(p.z);
      a[6] = dn * uplo(p.w); a[7] = dn * uphi(p.w);
    }
    int e = beg;
    for (; e + 2 <= end; e += 2) {
      const int s0 = esrc[e];
      const int s1 = esrc[e + 1];
      const float d0 = rsqrtf((float)(cursor[s0] - s0 * CAP) + 1.0f);
      const float d1 = rsqrtf((float)(cursor[s1] - s1 * CAP) + 1.0f);
      const uint4 q0 = *(const uint4*)&Y[(size_t)s0 * NC + c];
      const uint4 q1 = *(const uint4*)&Y[(size_t)s1 * NC + c];
      a[0] = fmaf(d0, uplo(q0.x), a[0]); a[1] = fmaf(d0, uphi(q0.x), a[1]);
      a[2] = fmaf(d0, uplo(q0.y), a[2]); a[3] = fmaf(d0, uphi(q0.y), a[3]);
      a[4] = fmaf(d0, uplo(q0.z), a[4]); a[5] = fmaf(d0, uphi(q0.z), a[5]);
      a[6] = fmaf(d0, uplo(q0.w), a[6]); a[7] = fmaf(d0, uphi(q0.w), a[7]);
      a[0] = fmaf(d1, uplo(q1.x), a[0]); a[1] = fmaf(d1, uphi(q1.x), a[1]);
      a[2] = fmaf(d1, uplo(q1.y), a[2]); a[3] = fmaf(d1, uphi(q1.y), a[3]);
      a[4] = fmaf(d1, uplo(q1.z), a[4]); a[5] = fmaf(d1, uphi(q1.z), a[5]);
      a[6] = fmaf(d1, uplo(q1.w), a[6]); a[7] = fmaf(d1, uphi(q1.w), a[7]);
    }
    if (e < end) {
      const int s0 = esrc[e];
      const float d0 = rsqrtf((float)(cursor[s0] - s0 * CAP) + 1.0f);
      const uint4 q0 = *(const uint4*)&Y[(size_t)s0 * NC + c];
      a[0] = fmaf(d0, uplo(q0.x), a[0]); a[1] = fmaf(d0, uphi(q0.x), a[1]);
      a[2] = fmaf(d0, uplo(q0.y), a[2]); a[3] = fmaf(d0, uphi(q0.y), a[3]);
      a[4] = fmaf(d0, uplo(q0.z), a[4]); a[5] = fmaf(d0, uphi(q0.z), a[5]);
      a[6] = fmaf(d0, uplo(q0.w), a[6]); a[7] = fmaf(d0, uphi(q0.w), a[7]);
    }
#pragma unroll
    for (int j = 0; j < 8; ++j) z[j] = fmaf(dn, a[j], cb[c + j]);
    if constexpr (OUTBF == 1) {
      unsigned int p[4];
#pragma unroll
      for (int j = 0; j < 4; ++j)
        p[j] = f2bf(z[2 * j]) | (f2bf(z[2 * j + 1]) << 16);
      *(uint4*)&((unsigned short*)outp)[(size_t)n * NC + c] =
          make_uint4(p[0], p[1], p[2], p[3]);
    } else {
      float* Z = (float*)outp;
      *(float4*)&Z[(size_t)n * NC + c] = make_float4(z[0], z[1], z[2], z[3]);
      *(float4*)&Z[(size_t)n * NC + c + 4] =
          make_float4(z[4], z[5], z[6], z[7]);
    }
  }
  float s[8], q[8];
#pragma unroll
  for (int j = 0; j < 8; ++j) { s[j] = z[j]; q[j] = z[j] * z[j]; }
#pragma unroll
  for (int off = CG; off < 64; off <<= 1) {
#pragma unroll
    for (int j = 0; j < 8; ++j) {
      s[j] += __shfl_xor(s[j], off);
      q[j] += __shfl_xor(q[j], off);
    }
  }
  const int w = tid >> 6;
  const int l = tid & 63;
  if (l < CG) {
    *(float4*)&ws_s[w][c] = make_float4(s[0], s[1], s[2], s[3]);
    *(float4*)&ws_s[w][c + 4] = make_float4(s[4], s[5], s[6], s[7]);
    *(float4*)&ws_q[w][c] = make_float4(q[0], q[1], q[2], q[3]);
    *(float4*)&ws_q[w][c + 4] = make_float4(q[4], q[5], q[6], q[7]);
  }
  __syncthreads();
  if (tid < NC) {
    float ts = 0.f, tq = 0.f;
#pragma unroll
    for (int g = 0; g < 4; ++g) { ts += ws_s[g][tid]; tq += ws_q[g][tid]; }
    const int bank = (blockIdx.x % NBANKG) * NC;
    atomicAdd(&sums[bank + tid], ts);
    atomicAdd(&sqs[bank + tid], tq);
  }
}

// ---------------- conv2 GEMM (bf16 in, affine+relu staging, bf16 out) ------
__global__ __launch_bounds__(256) void conv2_k(
    const unsigned short* __restrict__ Z1, const unsigned short* __restrict__ Wt,
    const float* __restrict__ sums, const float* __restrict__ sqs,
    const float* __restrict__ gamma, const float* __restrict__ beta,
    unsigned short* __restrict__ O1) {
  __shared__ __align__(16) char smem[16384];
  __shared__ float af_s[128];
  __shared__ float bf_s[128];
  const int tid = threadIdx.x;
  const int row0 = blockIdx.x * 64;
  if (tid < 128) {
    float s = 0.f, q = 0.f;
#pragma unroll
    for (int b = 0; b < NBANKG; ++b) {
      s += sums[b * 128 + tid];
      q += sqs[b * 128 + tid];
    }
    float m = s * (1.0f / NN);
    float v = q * (1.0f / NN) - m * m;
    float a = gamma[tid] * rsqrtf(v + BNEPS);
    af_s[tid] = a;
    bf_s[tid] = beta[tid] - m * a;
  }
  __syncthreads();
  for (int f = tid; f < 64 * 16; f += 256) {
    const int r = f >> 4;
    const int c8 = f & 15;
    const int rg = row0 + r;
    uint4 w4 = make_uint4(0u, 0u, 0u, 0u);
    if (rg < NN) {
      const uint4 raw = *(const uint4*)&Z1[(size_t)rg * 128 + c8 * 8];
      const int cc = c8 * 8;
      float e[8] = {uplo(raw.x), uphi(raw.x), uplo(raw.y), uphi(raw.y),
                    uplo(raw.z), uphi(raw.z), uplo(raw.w), uphi(raw.w)};
      unsigned int p[4];
#pragma unroll
      for (int j = 0; j < 4; ++j) {
        float lo = fmaxf(fmaf(af_s[cc + 2 * j], e[2 * j], bf_s[cc + 2 * j]), 0.f);
        float hi = fmaxf(
            fmaf(af_s[cc + 2 * j + 1], e[2 * j + 1], bf_s[cc + 2 * j + 1]), 0.f);
        p[j] = f2bf(lo) | (f2bf(hi) << 16);
      }
      w4 = make_uint4(p[0], p[1], p[2], p[3]);
    }
    const int ba = (r * 256 + c8 * 16) ^ ((r & 7) << 4);
    *(uint4*)(smem + ba) = w4;
  }
  __syncthreads();
  const int w = tid >> 6;
  const int l = tid & 63;
  const int lr = l & 15;
  const int lg = l >> 4;
  const int arow = w * 16 + lr;
  f32x4 acc[4];
#pragma unroll
  for (int i = 0; i < 4; ++i) acc[i] = (f32x4){0.f, 0.f, 0.f, 0.f};
#pragma unroll
  for (int kt = 0; kt < 4; ++kt) {
    const int ba = (arow * 256 + kt * 64 + lg * 16) ^ ((arow & 7) << 4);
    bf16x8 a = __builtin_bit_cast(bf16x8, *(const uint4*)(smem + ba));
#pragma unroll
    for (int nt = 0; nt < 4; ++nt) {
      bf16x8 b = __builtin_bit_cast(
          bf16x8,
          *(const uint4*)&Wt[(size_t)(nt * 16 + lr) * 128 + kt * 32 + lg * 8]);
      acc[nt] = __builtin_amdgcn_mfma_f32_16x16x32_bf16(a, b, acc[nt], 0, 0, 0);
    }
  }
  float* Cl = (float*)smem;
  const int tcx = tid % 16;
  const int trx = tid / 16;
#pragma unroll
  for (int half = 0; half < 2; ++half) {
    __syncthreads();
    if ((w >> 1) == half) {
#pragma unroll
      for (int nt = 0; nt < 4; ++nt)
#pragma unroll
        for (int r = 0; r < 4; ++r)
          Cl[((w & 1) * 16 + lg * 4 + r) * 68 + nt * 16 + lr] = acc[nt][r];
    }
    __syncthreads();
#pragma unroll
    for (int i = 0; i < 2; ++i) {
      const int rl = trx * 2 + i;
      const int rg = row0 + half * 32 + rl;
      if (rg < NN) {
        float4 v = *(const float4*)&Cl[rl * 68 + tcx * 4];
        uint2 o;
        o.x = f2bf(v.x) | (f2bf(v.y) << 16);
        o.y = f2bf(v.z) | (f2bf(v.w) << 16);
        *(uint2*)&O1[(size_t)rg * 64 + tcx * 4] = o;
      }
    }
  }
}

// ---------------- final: out = af*z2 + bf ----------------
__global__ __launch_bounds__(256) void final_k(
    const float* __restrict__ Z2, const float* __restrict__ s2,
    const float* __restrict__ q2, const float* __restrict__ gamma,
    const float* __restrict__ beta, float* __restrict__ out) {
  __shared__ float af_s[64];
  __shared__ float bf_s[64];
  if (threadIdx.x < 64) {
    float s = 0.f, q = 0.f;
#pragma unroll
    for (int b = 0; b < NBANKG; ++b) {
      s += s2[b * 64 + threadIdx.x];
      q += q2[b * 64 + threadIdx.x];
    }
    float m = s * (1.0f / NN);
    float v = q * (1.0f / NN) - m * m;
    float a = gamma[threadIdx.x] * rsqrtf(v + BNEPS);
    af_s[threadIdx.x] = a;
    bf_s[threadIdx.x] = beta[threadIdx.x] - m * a;
  }
  __syncthreads();
  const int u = blockIdx.x * 256 + threadIdx.x;
  if (u >= NN * 16) return;
  const int r = u >> 4;
  const int c = (u & 15) * 4;
  float4 v = *(const float4*)&Z2[(size_t)r * 64 + c];
  const float4 a4 = *(const float4*)&af_s[c];
  const float4 b4 = *(const float4*)&bf_s[c];
  float4 o;
  o.x = fmaf(a4.x, v.x, b4.x);
  o.y = fmaf(a4.y, v.y, b4.y);
  o.z = fmaf(a4.z, v.z, b4.z);
  o.w = fmaf(a4.w, v.w, b4.w);
  *(float4*)&out[(size_t)r * 64 + c] = o;
}

extern "C" void kernel_launch(void* const* d_in, const int* in_sizes, int n_in,
                              void* d_out, int out_size, void* d_ws,
                              size_t ws_size, hipStream_t stream) {
  const float* x = (const float*)d_in[0];
  const int* ei = (const int*)d_in[1];
  const int* src = ei;
  const int* dst = ei + NE;
  const float* bn_in_g = (const float*)d_in[2];
  const float* bn_in_b = (const float*)d_in[3];
  const float* bn1_g = (const float*)d_in[4];
  const float* bn1_b = (const float*)d_in[5];
  const float* bn2_g = (const float*)d_in[6];
  const float* bn2_b = (const float*)d_in[7];
  const float* proj_W = (const float*)d_in[8];
  const float* proj_b = (const float*)d_in[9];
  const float* conv1_W = (const float*)d_in[10];
  const float* conv1_b = (const float*)d_in[11];
  const float* conv2_W = (const float*)d_in[12];
  const float* conv2_b = (const float*)d_in[13];
  float* out = (float*)d_out;

  float* ws = (float*)d_ws;
  int* cursor = (int*)(ws + OFF_CURSOR);
  unsigned short* esrc = (unsigned short*)(ws + OFF_ESRC);  // padded ELL
  unsigned short* Wt0 = (unsigned short*)(ws + OFF_WT0);
  unsigned short* Wt1 = (unsigned short*)(ws + OFF_WT1);
  unsigned short* Wt2 = (unsigned short*)(ws + OFF_WT2);
  float* st = ws + OFF_STATS;
  float* s0 = st;              // 16 x 128
  float* q0 = st + 2048;       // 16 x 128
  float* s1 = st + 4096;       // 64 x 128
  float* q1 = st + 12288;      // 64 x 128
  float* s2 = st + 20480;      // 64 x 64
  float* q2 = st + 24576;      // 64 x 64
  int* bcur = (int*)(ws + OFF_BCUR);
  unsigned int* ebuf = (unsigned int*)(ws + OFF_EBUF);
  float* B0 = ws + OFF_B0;
  float* B1 = ws + OFF_B1;
  // sequential aliasing
  unsigned short* Ybf = (unsigned short*)B1;   // K2 out, gather1 in
  unsigned short* Z1bf = (unsigned short*)B0;  // gather1 out
  unsigned short* Y2bf = (unsigned short*)B1;  // conv2 out (Ybf dead)
  float* Z2 = B0;                              // gather2 out (Z1 dead)

  // K0: wtrans + cursor init + zero stats + zero bucket cursors
  prep_k<<<476, 256, 0, stream>>>(proj_W, conv1_W, conv2_W, Wt0, Wt1, Wt2,
                                  cursor, st, bcur);
  // K1: bn_stats(x) [1024, 16-bank] ∥ bucket pass A [2500, 2048 buckets]
  stats_bucketA_k<<<3524, 256, 0, stream>>>(x, s0, q0, src, dst, bcur, ebuf);
  // K2: fused GEMM1→LDS→conv1 → Ybf [782] ∥ bucket pass B → ELL [2048]
  fused12_bucketB_k<<<2830, 256, 0, stream>>>(x, Wt0, Wt1, proj_b, s0, q0,
                                              bn_in_g, bn_in_b, Ybf, bcur,
                                              ebuf, cursor, esrc);
  // K3: gather1 → z1 bf16 + fused BN1 stats [3125, 64-bank]
  gather_bf_k<128, 1><<<3125, 256, 0, stream>>>(cursor, esrc, Ybf, Z1bf,
                                                conv1_b, s1, q1);
  // K4: conv2 GEMM (relu(BN1(z1)) staging, plain bf16 out)
  conv2_k<<<782, 256, 0, stream>>>(Z1bf, Wt2, s1, q1, bn1_g, bn1_b, Y2bf);
  // K5: gather2 → z2 f32 + fused BN2 stats [1563, 64-bank]
  gather_bf_k<64, 0><<<1563, 256, 0, stream>>>(cursor, esrc, Y2bf, Z2, conv2_b,
                                               s2, q2);
  // K6: final BN apply (pure affine on z2)
  final_k<<<(NN * 16 + 255) / 256, 256, 0, stream>>>(Z2, s2, q2, bn2_g, bn2_b,
                                                     out);
}

// Round 29
// 151.033 us; speedup vs baseline: 2.7595x; 1.4243x over previous
//
#include <hip/hip_runtime.h>

#define NN 50000
#define NE 640000
#define BNEPS 1e-5f
#define NBANK 16   // banks for stats(x)
#define NBANKG 64  // banks for gather-fused stats
#define CAP 64     // padded ELL row capacity (λ=12.8, max deg ≈ 30)

// workspace layout (float offsets) — total 14,555,648 floats = 58.2 MB
#define OFF_CURSOR 51200
#define OFF_ESRC 102400      // NN*CAP ushorts = 1.6M floats
#define OFF_WT0 1702400
#define OFF_WT1 1710592
#define OFF_WT2 1718784
#define OFF_STATS 1726976    // 28672 floats
#define OFF_B0 1755648
#define OFF_B1 8155648

typedef __attribute__((ext_vector_type(8))) __bf16 bf16x8;
typedef __attribute__((ext_vector_type(4))) float f32x4;

// ---- bf16 helpers ----
__device__ __forceinline__ float uplo(unsigned int u) {
  unsigned int v = u << 16;
  return __builtin_bit_cast(float, v);
}
__device__ __forceinline__ float uphi(unsigned int u) {
  unsigned int v = u & 0xffff0000u;
  return __builtin_bit_cast(float, v);
}
__device__ __forceinline__ unsigned int f2bf(float f) {
  unsigned int u = __builtin_bit_cast(unsigned int, f);
  return (u + 0x7fffu + ((u >> 16) & 1u)) >> 16;  // RNE
}

// ====== K0: weight transpose + cursor init (n*CAP) + zero stats ============
__global__ __launch_bounds__(256) void prep_k(
    const float* __restrict__ W0, const float* __restrict__ W1,
    const float* __restrict__ W2, unsigned short* __restrict__ T0,
    unsigned short* __restrict__ T1, unsigned short* __restrict__ T2,
    int* __restrict__ cursor, float* __restrict__ stats) {
  const int bid = blockIdx.x;
  const int tid = threadIdx.x;
  if (bid < 160) {
    int f = bid * 256 + tid;
    if (f < 16384) {
      int k = f >> 7, n = f & 127;
      T0[n * 128 + k] = (unsigned short)f2bf(W0[f]);
    } else if (f < 32768) {
      int g = f - 16384;
      int k = g >> 7, n = g & 127;
      T1[n * 128 + k] = (unsigned short)f2bf(W1[g]);
    } else if (f < 40960) {
      int g = f - 32768;
      int k = g >> 6, n = g & 63;
      T2[n * 128 + k] = (unsigned short)f2bf(W2[g]);
    }
  } else if (bid < 356) {
    int i = (bid - 160) * 256 + tid;
    if (i < NN) cursor[i] = i * CAP;
  } else {
    int j = (bid - 356) * 256 + tid;  // 112 blocks x 256 = 28672 exactly
    stats[j] = 0.0f;
  }
}

// ---- BN-stats on x (f32, 16 banks) ----
__device__ __forceinline__ void statsx_body(int sbid, int tid,
                                            const float* __restrict__ A,
                                            float* __restrict__ sums,
                                            float* __restrict__ sqs,
                                            float (*rs)[128],
                                            float (*rq)[128]) {
  const int tc = tid % 32;
  const int tr = tid / 32;
  float s0 = 0, s1 = 0, s2 = 0, s3 = 0, q0 = 0, q1 = 0, q2 = 0, q3 = 0;
  for (int r = sbid * 8 + tr; r < NN; r += 1024 * 8) {
    float4 v = *(const float4*)&A[(size_t)r * 128 + tc * 4];
    s0 += v.x; s1 += v.y; s2 += v.z; s3 += v.w;
    q0 += v.x * v.x; q1 += v.y * v.y; q2 += v.z * v.z; q3 += v.w * v.w;
  }
  rs[tr][tc * 4] = s0; rs[tr][tc * 4 + 1] = s1;
  rs[tr][tc * 4 + 2] = s2; rs[tr][tc * 4 + 3] = s3;
  rq[tr][tc * 4] = q0; rq[tr][tc * 4 + 1] = q1;
  rq[tr][tc * 4 + 2] = q2; rq[tr][tc * 4 + 3] = q3;
  __syncthreads();
  if (tr == 0) {
    const int bank = (sbid & (NBANK - 1)) * 128;
    for (int j = 0; j < 4; ++j) {
      int c = tc * 4 + j;
      float ts = 0, tq = 0;
      for (int g = 0; g < 8; ++g) { ts += rs[g][c]; tq += rq[g][c]; }
      atomicAdd(&sums[bank + c], ts);
      atomicAdd(&sqs[bank + c], tq);
    }
  }
}

// ===== K1: bn_stats(x) [1024] ∥ ELL fill first half [1250] =================
__global__ __launch_bounds__(256) void stats_fill_k(
    const float* __restrict__ x, float* __restrict__ s0,
    float* __restrict__ q0, const int* __restrict__ src,
    const int* __restrict__ dst, int* __restrict__ cursor,
    unsigned short* __restrict__ esrc) {
  __shared__ float rs[8][128];
  __shared__ float rq[8][128];
  const int bid = blockIdx.x;
  if (bid < 1024) {
    statsx_body(bid, threadIdx.x, x, s0, q0, rs, rq);
  } else {
    int e = (bid - 1024) * 256 + threadIdx.x;  // edges [0, NE/2)
    if (e < NE / 2) {
      int p = atomicAdd(&cursor[dst[e]], 1);
      esrc[p] = (unsigned short)src[e];
    }
  }
}

// ===== K2: fused GEMM1→LDS→conv1 [782] ∥ ELL fill second half [1250] =======
__global__ __launch_bounds__(256) void fused12_fill_k(
    const float* __restrict__ x, const unsigned short* __restrict__ Wt0,
    const unsigned short* __restrict__ Wt1, const float* __restrict__ proj_b,
    const float* __restrict__ s0, const float* __restrict__ q0,
    const float* __restrict__ g0, const float* __restrict__ b0,
    unsigned short* __restrict__ Ybf, const int* __restrict__ src,
    const int* __restrict__ dst, int* __restrict__ cursor,
    unsigned short* __restrict__ esrc) {
  __shared__ __align__(16) char smem[17408];
  __shared__ float af_s[128];
  __shared__ float bf_s[128];
  __shared__ float pb_s[128];
  const int bid = blockIdx.x;
  const int tid = threadIdx.x;
  if (bid >= 782) {
    int e = NE / 2 + (bid - 782) * 256 + tid;  // edges [NE/2, NE)
    if (e < NE) {
      int p = atomicAdd(&cursor[dst[e]], 1);
      esrc[p] = (unsigned short)src[e];
    }
    return;
  }
  const int row0 = bid * 64;
  if (tid < 128) {
    float s = 0.f, q = 0.f;
#pragma unroll
    for (int b = 0; b < NBANK; ++b) {
      s += s0[b * 128 + tid];
      q += q0[b * 128 + tid];
    }
    float m = s * (1.0f / NN);
    float v = q * (1.0f / NN) - m * m;
    float a = g0[tid] * rsqrtf(v + BNEPS);
    af_s[tid] = a;
    bf_s[tid] = b0[tid] - m * a;
    pb_s[tid] = proj_b[tid];
  }
  __syncthreads();
  // stage A-tile: bf16(BN(x)) swizzled into LDS
  for (int f = tid; f < 64 * 32; f += 256) {
    const int r = f >> 5;
    const int c4 = f & 31;
    const int rg = row0 + r;
    float4 v = make_float4(0.f, 0.f, 0.f, 0.f);
    if (rg < NN) {
      v = *(const float4*)&x[(size_t)rg * 128 + c4 * 4];
      const float4 a4 = *(const float4*)&af_s[c4 * 4];
      const float4 b4 = *(const float4*)&bf_s[c4 * 4];
      v.x = fmaf(a4.x, v.x, b4.x);
      v.y = fmaf(a4.y, v.y, b4.y);
      v.z = fmaf(a4.z, v.z, b4.z);
      v.w = fmaf(a4.w, v.w, b4.w);
    }
    uint2 wv;
    wv.x = f2bf(v.x) | (f2bf(v.y) << 16);
    wv.y = f2bf(v.z) | (f2bf(v.w) << 16);
    const int ba = (r * 256 + c4 * 8) ^ ((r & 7) << 4);
    *(uint2*)(smem + ba) = wv;
  }
  __syncthreads();

  const int w = tid >> 6;
  const int l = tid & 63;
  const int lr = l & 15;
  const int lg = l >> 4;
  const int arow = w * 16 + lr;
  // ---- stage 1 MFMA: acc = BN(x) @ W0 ----
  f32x4 acc[8];
#pragma unroll
  for (int i = 0; i < 8; ++i) acc[i] = (f32x4){0.f, 0.f, 0.f, 0.f};
#pragma unroll
  for (int kt = 0; kt < 4; ++kt) {
    const int ba = (arow * 256 + kt * 64 + lg * 16) ^ ((arow & 7) << 4);
    bf16x8 a = __builtin_bit_cast(bf16x8, *(const uint4*)(smem + ba));
#pragma unroll
    for (int nt = 0; nt < 8; ++nt) {
      bf16x8 b = __builtin_bit_cast(
          bf16x8,
          *(const uint4*)&Wt0[(size_t)(nt * 16 + lr) * 128 + kt * 32 + lg * 8]);
      acc[nt] = __builtin_amdgcn_mfma_f32_16x16x32_bf16(a, b, acc[nt], 0, 0, 0);
    }
  }
  __syncthreads();
  // ---- H = relu(acc + proj_b) -> bf16 LDS (same swizzled layout) ----
#pragma unroll
  for (int nt = 0; nt < 8; ++nt) {
    const float pb = pb_s[nt * 16 + lr];
#pragma unroll
    for (int r = 0; r < 4; ++r) {
      const int row = w * 16 + lg * 4 + r;
      const float hv = fmaxf(acc[nt][r] + pb, 0.f);
      const int ba = (row * 256 + (nt * 16 + lr) * 2) ^ ((row & 7) << 4);
      *(unsigned short*)(smem + ba) = (unsigned short)f2bf(hv);
    }
  }
  __syncthreads();
  // ---- stage 2 MFMA: acc2 = H @ W1 ----
  f32x4 acc2[8];
#pragma unroll
  for (int i = 0; i < 8; ++i) acc2[i] = (f32x4){0.f, 0.f, 0.f, 0.f};
#pragma unroll
  for (int kt = 0; kt < 4; ++kt) {
    const int ba = (arow * 256 + kt * 64 + lg * 16) ^ ((arow & 7) << 4);
    bf16x8 a = __builtin_bit_cast(bf16x8, *(const uint4*)(smem + ba));
#pragma unroll
    for (int nt = 0; nt < 8; ++nt) {
      bf16x8 b = __builtin_bit_cast(
          bf16x8,
          *(const uint4*)&Wt1[(size_t)(nt * 16 + lr) * 128 + kt * 32 + lg * 8]);
      acc2[nt] =
          __builtin_amdgcn_mfma_f32_16x16x32_bf16(a, b, acc2[nt], 0, 0, 0);
    }
  }
  // ---- chunked repack -> Ybf (plain bf16) ----
  float* Cl = (float*)smem;
  const int tcx = tid % 32;  // CG = 32
  const int trx = tid / 32;
#pragma unroll
  for (int half = 0; half < 2; ++half) {
    __syncthreads();
    if ((w >> 1) == half) {
#pragma unroll
      for (int nt = 0; nt < 8; ++nt)
#pragma unroll
        for (int r = 0; r < 4; ++r)
          Cl[((w & 1) * 16 + lg * 4 + r) * 132 + nt * 16 + lr] = acc2[nt][r];
    }
    __syncthreads();
#pragma unroll
    for (int i = 0; i < 4; ++i) {
      const int rl = trx * 4 + i;
      const int rg = row0 + half * 32 + rl;
      if (rg < NN) {
        float4 v = *(const float4*)&Cl[rl * 132 + tcx * 4];
        uint2 o;
        o.x = f2bf(v.x) | (f2bf(v.y) << 16);
        o.y = f2bf(v.z) | (f2bf(v.w) << 16);
        *(uint2*)&Ybf[(size_t)rg * 128 + tcx * 4] = o;
      }
    }
  }
}

// ======= gather + fused BN stats (shfl row-reduce, conflict-free LDS) ======
// acc = dinv[n]*Y[n] + Σ dinv[s]*Y[s];  z = dinv[n]*acc + cb[c]
// OUTBF=1: store z as bf16 ; OUTBF=0: store z as f32
template <int NC, int OUTBF>
__global__ __launch_bounds__(256) void gather_bf_k(
    const int* __restrict__ cursor, const unsigned short* __restrict__ esrc,
    const unsigned short* __restrict__ Y, void* __restrict__ outp,
    const float* __restrict__ cb, float* __restrict__ sums,
    float* __restrict__ sqs) {
  constexpr int CG = NC / 8;
  constexpr int RG = 256 / CG;
  __shared__ float ws_s[4][NC];
  __shared__ float ws_q[4][NC];
  const int tid = threadIdx.x;
  const int tc = tid % CG;
  const int tr = tid / CG;
  const int n = blockIdx.x * RG + tr;
  const bool act = (n < NN);
  const int c = tc * 8;
  float z[8];
#pragma unroll
  for (int j = 0; j < 8; ++j) z[j] = 0.f;
  if (act) {
    const int beg = n * CAP;
    const int end = cursor[n];
    const float dn = rsqrtf((float)(end - beg) + 1.0f);
    float a[8];
    {
      const uint4 p = *(const uint4*)&Y[(size_t)n * NC + c];
      a[0] = dn * uplo(p.x); a[1] = dn * uphi(p.x);
      a[2] = dn * uplo(p.y); a[3] = dn * uphi(p.y);
      a[4] = dn * uplo(p.z); a[5] = dn * uphi(p.z);
      a[6] = dn * uplo(p.w); a[7] = dn * uphi(p.w);
    }
    int e = beg;
    for (; e + 2 <= end; e += 2) {
      const int s0 = esrc[e];
      const int s1 = esrc[e + 1];
      const float d0 = rsqrtf((float)(cursor[s0] - s0 * CAP) + 1.0f);
      const float d1 = rsqrtf((float)(cursor[s1] - s1 * CAP) + 1.0f);
      const uint4 q0 = *(const uint4*)&Y[(size_t)s0 * NC + c];
      const uint4 q1 = *(const uint4*)&Y[(size_t)s1 * NC + c];
      a[0] = fmaf(d0, uplo(q0.x), a[0]); a[1] = fmaf(d0, uphi(q0.x), a[1]);
      a[2] = fmaf(d0, uplo(q0.y), a[2]); a[3] = fmaf(d0, uphi(q0.y), a[3]);
      a[4] = fmaf(d0, uplo(q0.z), a[4]); a[5] = fmaf(d0, uphi(q0.z), a[5]);
      a[6] = fmaf(d0, uplo(q0.w), a[6]); a[7] = fmaf(d0, uphi(q0.w), a[7]);
      a[0] = fmaf(d1, uplo(q1.x), a[0]); a[1] = fmaf(d1, uphi(q1.x), a[1]);
      a[2] = fmaf(d1, uplo(q1.y), a[2]); a[3] = fmaf(d1, uphi(q1.y), a[3]);
      a[4] = fmaf(d1, uplo(q1.z), a[4]); a[5] = fmaf(d1, uphi(q1.z), a[5]);
      a[6] = fmaf(d1, uplo(q1.w), a[6]); a[7] = fmaf(d1, uphi(q1.w), a[7]);
    }
    if (e < end) {
      const int s0 = esrc[e];
      const float d0 = rsqrtf((float)(cursor[s0] - s0 * CAP) + 1.0f);
      const uint4 q0 = *(const uint4*)&Y[(size_t)s0 * NC + c];
      a[0] = fmaf(d0, uplo(q0.x), a[0]); a[1] = fmaf(d0, uphi(q0.x), a[1]);
      a[2] = fmaf(d0, uplo(q0.y), a[2]); a[3] = fmaf(d0, uphi(q0.y), a[3]);
      a[4] = fmaf(d0, uplo(q0.z), a[4]); a[5] = fmaf(d0, uphi(q0.z), a[5]);
      a[6] = fmaf(d0, uplo(q0.w), a[6]); a[7] = fmaf(d0, uphi(q0.w), a[7]);
    }
#pragma unroll
    for (int j = 0; j < 8; ++j) z[j] = fmaf(dn, a[j], cb[c + j]);
    if constexpr (OUTBF == 1) {
      unsigned int p[4];
#pragma unroll
      for (int j = 0; j < 4; ++j)
        p[j] = f2bf(z[2 * j]) | (f2bf(z[2 * j + 1]) << 16);
      *(uint4*)&((unsigned short*)outp)[(size_t)n * NC + c] =
          make_uint4(p[0], p[1], p[2], p[3]);
    } else {
      float* Z = (float*)outp;
      *(float4*)&Z[(size_t)n * NC + c] = make_float4(z[0], z[1], z[2], z[3]);
      *(float4*)&Z[(size_t)n * NC + c + 4] =
          make_float4(z[4], z[5], z[6], z[7]);
    }
  }
  // ---- fused stats: wave shfl row-reduce -> per-wave LDS -> banked atomics
  float s[8], q[8];
#pragma unroll
  for (int j = 0; j < 8; ++j) { s[j] = z[j]; q[j] = z[j] * z[j]; }
#pragma unroll
  for (int off = CG; off < 64; off <<= 1) {
#pragma unroll
    for (int j = 0; j < 8; ++j) {
      s[j] += __shfl_xor(s[j], off);
      q[j] += __shfl_xor(q[j], off);
    }
  }
  const int w = tid >> 6;
  const int l = tid & 63;
  if (l < CG) {
    *(float4*)&ws_s[w][c] = make_float4(s[0], s[1], s[2], s[3]);
    *(float4*)&ws_s[w][c + 4] = make_float4(s[4], s[5], s[6], s[7]);
    *(float4*)&ws_q[w][c] = make_float4(q[0], q[1], q[2], q[3]);
    *(float4*)&ws_q[w][c + 4] = make_float4(q[4], q[5], q[6], q[7]);
  }
  __syncthreads();
  if (tid < NC) {
    float ts = 0.f, tq = 0.f;
#pragma unroll
    for (int g = 0; g < 4; ++g) { ts += ws_s[g][tid]; tq += ws_q[g][tid]; }
    const int bank = (blockIdx.x % NBANKG) * NC;
    atomicAdd(&sums[bank + tid], ts);
    atomicAdd(&sqs[bank + tid], tq);
  }
}

// ---------------- conv2 GEMM (bf16 in, affine+relu staging, bf16 out) ------
__global__ __launch_bounds__(256) void conv2_k(
    const unsigned short* __restrict__ Z1, const unsigned short* __restrict__ Wt,
    const float* __restrict__ sums, const float* __restrict__ sqs,
    const float* __restrict__ gamma, const float* __restrict__ beta,
    unsigned short* __restrict__ O1) {
  __shared__ __align__(16) char smem[16384];
  __shared__ float af_s[128];
  __shared__ float bf_s[128];
  const int tid = threadIdx.x;
  const int row0 = blockIdx.x * 64;
  if (tid < 128) {
    float s = 0.f, q = 0.f;
#pragma unroll
    for (int b = 0; b < NBANKG; ++b) {
      s += sums[b * 128 + tid];
      q += sqs[b * 128 + tid];
    }
    float m = s * (1.0f / NN);
    float v = q * (1.0f / NN) - m * m;
    float a = gamma[tid] * rsqrtf(v + BNEPS);
    af_s[tid] = a;
    bf_s[tid] = beta[tid] - m * a;
  }
  __syncthreads();
  for (int f = tid; f < 64 * 16; f += 256) {
    const int r = f >> 4;
    const int c8 = f & 15;
    const int rg = row0 + r;
    uint4 w4 = make_uint4(0u, 0u, 0u, 0u);
    if (rg < NN) {
      const uint4 raw = *(const uint4*)&Z1[(size_t)rg * 128 + c8 * 8];
      const int cc = c8 * 8;
      float e[8] = {uplo(raw.x), uphi(raw.x), uplo(raw.y), uphi(raw.y),
                    uplo(raw.z), uphi(raw.z), uplo(raw.w), uphi(raw.w)};
      unsigned int p[4];
#pragma unroll
      for (int j = 0; j < 4; ++j) {
        float lo = fmaxf(fmaf(af_s[cc + 2 * j], e[2 * j], bf_s[cc + 2 * j]), 0.f);
        float hi = fmaxf(
            fmaf(af_s[cc + 2 * j + 1], e[2 * j + 1], bf_s[cc + 2 * j + 1]), 0.f);
        p[j] = f2bf(lo) | (f2bf(hi) << 16);
      }
      w4 = make_uint4(p[0], p[1], p[2], p[3]);
    }
    const int ba = (r * 256 + c8 * 16) ^ ((r & 7) << 4);
    *(uint4*)(smem + ba) = w4;
  }
  __syncthreads();
  const int w = tid >> 6;
  const int l = tid & 63;
  const int lr = l & 15;
  const int lg = l >> 4;
  const int arow = w * 16 + lr;
  f32x4 acc[4];
#pragma unroll
  for (int i = 0; i < 4; ++i) acc[i] = (f32x4){0.f, 0.f, 0.f, 0.f};
#pragma unroll
  for (int kt = 0; kt < 4; ++kt) {
    const int ba = (arow * 256 + kt * 64 + lg * 16) ^ ((arow & 7) << 4);
    bf16x8 a = __builtin_bit_cast(bf16x8, *(const uint4*)(smem + ba));
#pragma unroll
    for (int nt = 0; nt < 4; ++nt) {
      bf16x8 b = __builtin_bit_cast(
          bf16x8,
          *(const uint4*)&Wt[(size_t)(nt * 16 + lr) * 128 + kt * 32 + lg * 8]);
      acc[nt] = __builtin_amdgcn_mfma_f32_16x16x32_bf16(a, b, acc[nt], 0, 0, 0);
    }
  }
  // chunked repack (NC=64, CSTR=68)
  float* Cl = (float*)smem;
  const int tcx = tid % 16;
  const int trx = tid / 16;
#pragma unroll
  for (int half = 0; half < 2; ++half) {
    __syncthreads();
    if ((w >> 1) == half) {
#pragma unroll
      for (int nt = 0; nt < 4; ++nt)
#pragma unroll
        for (int r = 0; r < 4; ++r)
          Cl[((w & 1) * 16 + lg * 4 + r) * 68 + nt * 16 + lr] = acc[nt][r];
    }
    __syncthreads();
#pragma unroll
    for (int i = 0; i < 2; ++i) {
      const int rl = trx * 2 + i;
      const int rg = row0 + half * 32 + rl;
      if (rg < NN) {
        float4 v = *(const float4*)&Cl[rl * 68 + tcx * 4];
        uint2 o;
        o.x = f2bf(v.x) | (f2bf(v.y) << 16);
        o.y = f2bf(v.z) | (f2bf(v.w) << 16);
        *(uint2*)&O1[(size_t)rg * 64 + tcx * 4] = o;
      }
    }
  }
}

// ---------------- final: out = af*z2 + bf ----------------
__global__ __launch_bounds__(256) void final_k(
    const float* __restrict__ Z2, const float* __restrict__ s2,
    const float* __restrict__ q2, const float* __restrict__ gamma,
    const float* __restrict__ beta, float* __restrict__ out) {
  __shared__ float af_s[64];
  __shared__ float bf_s[64];
  if (threadIdx.x < 64) {
    float s = 0.f, q = 0.f;
#pragma unroll
    for (int b = 0; b < 64; ++b) {
      s += s2[b * 64 + threadIdx.x];
      q += q2[b * 64 + threadIdx.x];
    }
    float m = s * (1.0f / NN);
    float v = q * (1.0f / NN) - m * m;
    float a = gamma[threadIdx.x] * rsqrtf(v + BNEPS);
    af_s[threadIdx.x] = a;
    bf_s[threadIdx.x] = beta[threadIdx.x] - m * a;
  }
  __syncthreads();
  const int u = blockIdx.x * 256 + threadIdx.x;
  if (u >= NN * 16) return;
  const int r = u >> 4;
  const int c = (u & 15) * 4;
  float4 v = *(const float4*)&Z2[(size_t)r * 64 + c];
  const float4 a4 = *(const float4*)&af_s[c];
  const float4 b4 = *(const float4*)&bf_s[c];
  float4 o;
  o.x = fmaf(a4.x, v.x, b4.x);
  o.y = fmaf(a4.y, v.y, b4.y);
  o.z = fmaf(a4.z, v.z, b4.z);
  o.w = fmaf(a4.w, v.w, b4.w);
  *(float4*)&out[(size_t)r * 64 + c] = o;
}

extern "C" void kernel_launch(void* const* d_in, const int* in_sizes, int n_in,
                              void* d_out, int out_size, void* d_ws,
                              size_t ws_size, hipStream_t stream) {
  const float* x = (const float*)d_in[0];
  const int* ei = (const int*)d_in[1];
  const int* src = ei;
  const int* dst = ei + NE;
  const float* bn_in_g = (const float*)d_in[2];
  const float* bn_in_b = (const float*)d_in[3];
  const float* bn1_g = (const float*)d_in[4];
  const float* bn1_b = (const float*)d_in[5];
  const float* bn2_g = (const float*)d_in[6];
  const float* bn2_b = (const float*)d_in[7];
  const float* proj_W = (const float*)d_in[8];
  const float* proj_b = (const float*)d_in[9];
  const float* conv1_W = (const float*)d_in[10];
  const float* conv1_b = (const float*)d_in[11];
  const float* conv2_W = (const float*)d_in[12];
  const float* conv2_b = (const float*)d_in[13];
  float* out = (float*)d_out;

  float* ws = (float*)d_ws;
  int* cursor = (int*)(ws + OFF_CURSOR);
  unsigned short* esrc = (unsigned short*)(ws + OFF_ESRC);  // padded ELL
  unsigned short* Wt0 = (unsigned short*)(ws + OFF_WT0);
  unsigned short* Wt1 = (unsigned short*)(ws + OFF_WT1);
  unsigned short* Wt2 = (unsigned short*)(ws + OFF_WT2);
  float* st = ws + OFF_STATS;  // banked stats, zeroed by prep_k
  float* s0 = st;              // 16 x 128
  float* q0 = st + 2048;       // 16 x 128
  float* s1 = st + 4096;       // 64 x 128
  float* q1 = st + 12288;      // 64 x 128
  float* s2 = st + 20480;      // 64 x 64
  float* q2 = st + 24576;      // 64 x 64
  float* B0 = ws + OFF_B0;
  float* B1 = ws + OFF_B1;
  // sequential aliasing: each buffer generation fully written before read
  unsigned short* Ybf = (unsigned short*)B1;   // K2 out, gather1 in
  unsigned short* Z1bf = (unsigned short*)B0;  // gather1 out
  unsigned short* Y2bf = (unsigned short*)B1;  // conv2 out (Ybf dead)
  float* Z2 = B0;                              // gather2 out (Z1 dead)

  // K0: weight transpose + cursor init + zero stats
  prep_k<<<468, 256, 0, stream>>>(proj_W, conv1_W, conv2_W, Wt0, Wt1, Wt2,
                                  cursor, st);
  // K1: bn_stats(x) [1024, 16-bank] ∥ ELL fill first half [1250]
  stats_fill_k<<<2274, 256, 0, stream>>>(x, s0, q0, src, dst, cursor, esrc);
  // K2: fused GEMM1→LDS→conv1 → Ybf [782] ∥ ELL fill second half [1250]
  fused12_fill_k<<<2032, 256, 0, stream>>>(x, Wt0, Wt1, proj_b, s0, q0,
                                           bn_in_g, bn_in_b, Ybf, src, dst,
                                           cursor, esrc);
  // K3: gather1 → z1 bf16 + fused BN1 stats [3125, 64-bank]
  gather_bf_k<128, 1><<<3125, 256, 0, stream>>>(cursor, esrc, Ybf, Z1bf,
                                                conv1_b, s1, q1);
  // K4: conv2 GEMM (relu(BN1(z1)) staging, plain bf16 out)
  conv2_k<<<782, 256, 0, stream>>>(Z1bf, Wt2, s1, q1, bn1_g, bn1_b, Y2bf);
  // K5: gather2 → z2 f32 + fused BN2 stats [1563, 64-bank]
  gather_bf_k<64, 0><<<1563, 256, 0, stream>>>(cursor, esrc, Y2bf, Z2, conv2_b,
                                               s2, q2);
  // K6: final BN apply (pure affine on z2)
  final_k<<<(NN * 16 + 255) / 256, 256, 0, stream>>>(Z2, s2, q2, bn2_g, bn2_b,
                                                     out);
}